// Round 7
// baseline (641.919 us; speedup 1.0000x reference)
//
#include <hip/hip_runtime.h>
#include <stdint.h>

typedef unsigned long long u64;
typedef unsigned int u32;
typedef unsigned short u16;
typedef unsigned char u8;
typedef signed char s8;

#define NB 4096

// ---------------- workspace layout (bytes) ----------------
#define WS_STATS 0          // long long[288*8]
#define WS_W1Q   20480      // u32[240]
#define WS_W2P   24576      // u64[432]
#define WS_W3P   28672      // u64[432]
#define WS_WFCP  32768      // u64[205]
#define WS_A2    40960      // u64[4096*154] -> ends 5,087,232
#define WS_P1    5087232    // u8[4096*8448] padded [48][11][16] -> ends 39,690,240
#define WS_P3    5087232    // int[4096*1440] (written by kB after P1 is dead)

// ---------------- d_out offsets (floats) ----------------
#define OUT_OFF 0
#define XB1_OFF 20480
#define XB2_OFF 8867840
#define XB3_OFF 39145472
#define FB_OFF  60379136

__device__ __forceinline__ float fsign(float v) {
    return (v > 0.0f) ? 1.0f : ((v < 0.0f) ? -1.0f : 0.0f);
}
__device__ __forceinline__ int sh16(int v, int h) {
    return h ? (v >> 16) : (int)(short)v;
}

// ---- weight binarize+pack, stats zero ----
__global__ __launch_bounds__(512)
void kw_pack(const float* __restrict__ w1, const float* __restrict__ w2,
             const float* __restrict__ w3, const float* __restrict__ wfc,
             u32* __restrict__ W1Q, u64* __restrict__ W2P, u64* __restrict__ W3P,
             u64* __restrict__ WFCP, long long* __restrict__ stats) {
    int t = threadIdx.x;
    for (int i = t; i < 2304; i += 512) stats[i] = 0;
    if (t < 48) {
        u16 m1[9];
        #pragma unroll
        for (int p = 0; p < 9; ++p) {
            u16 m = 0;
            for (int c = 0; c < 12; ++c)
                if (w1[t*108 + c*9 + p] > 0.0f) m |= (u16)(1u << c);
            m1[p] = m;
        }
        #pragma unroll
        for (int j = 0; j < 4; ++j)
            W1Q[t*5 + j] = (u32)m1[2*j] | ((u32)m1[2*j+1] << 16);
        W1Q[t*5 + 4] = (u32)m1[8];
    }
    if (t < 432) {
        int oc = t / 9, p = t % 9;
        u64 m2 = 0, m3 = 0;
        for (int c = 0; c < 48; ++c) {
            if (w2[oc*432 + c*9 + p] > 0.0f) m2 |= (1ull << c);
            if (w3[oc*432 + c*9 + p] > 0.0f) m3 |= (1ull << c);
        }
        W2P[t] = m2;
        W3P[t] = m3;
    }
    if (t < 205) {
        int o = t / 41, j = t % 41;
        u64 m = 0;
        for (int l = 0; l < 64; ++l) {
            int k = j*64 + l;
            if (k < 2592 && wfc[o*2592 + k] > 0.0f) m |= (1ull << l);
        }
        WFCP[t] = m;
    }
}

// ---- binarize x -> xb1 (float4), conv1 (pad1), pool -> P1, stats1 ----
__global__ __launch_bounds__(192)
void k1(const float* __restrict__ x, const u32* __restrict__ W1Q,
        float* __restrict__ dout, u8* __restrict__ P1g, u64* __restrict__ stats) {
    __shared__ u8 bitsb[2160];
    __shared__ u16 As[180];
    __shared__ int cmap[2304];   // s8 [48][12][16]
    __shared__ int2 part[192];
    int t = threadIdx.x, b = blockIdx.x;
    // phase0: vectorized binarize x -> xb1 + sign bits in LDS
    {
        const float4* xp = (const float4*)(x + (size_t)b*2160);
        float4* xo = (float4*)(dout + XB1_OFF + (size_t)b*2160);
        for (int j = t; j < 540; j += 192) {
            float4 v = xp[j];
            float4 o;
            o.x = fsign(v.x); o.y = fsign(v.y); o.z = fsign(v.z); o.w = fsign(v.w);
            xo[j] = o;
            bitsb[4*j]   = v.x > 0.0f;
            bitsb[4*j+1] = v.y > 0.0f;
            bitsb[4*j+2] = v.z > 0.0f;
            bitsb[4*j+3] = v.w > 0.0f;
        }
    }
    __syncthreads();
    if (t < 180) {
        u16 m = 0;
        #pragma unroll
        for (int c = 0; c < 12; ++c)
            m |= ((u16)bitsb[c*180 + t]) << c;
        As[t] = m;
    }
    __syncthreads();
    // phase1: conv1, packed popc
    if (t < 180) {
        int y = t / 15, xx = t % 15;
        u16 tap[9], msk[9];
        int nv = 0;
        #pragma unroll
        for (int ky = 0; ky < 3; ++ky) {
            #pragma unroll
            for (int kx = 0; kx < 3; ++kx) {
                int yy = y + ky - 1, xc = xx + kx - 1;
                bool v = (yy >= 0 && yy < 12 && xc >= 0 && xc < 15);
                int yl = min(max(yy, 0), 11), xl = min(max(xc, 0), 14);
                tap[ky*3+kx] = As[yl*15 + xl];
                msk[ky*3+kx] = v ? (u16)0xFFFF : (u16)0;
                nv += v ? 12 : 0;
            }
        }
        u32 tq[5], mq[5];
        #pragma unroll
        for (int j = 0; j < 4; ++j) {
            tq[j] = (u32)tap[2*j] | ((u32)tap[2*j+1] << 16);
            mq[j] = (u32)msk[2*j] | ((u32)msk[2*j+1] << 16);
        }
        tq[4] = tap[8]; mq[4] = msk[8];
        s8* cb = (s8*)cmap;
        #pragma unroll 4
        for (int oc = 0; oc < 48; ++oc) {
            int acc = 0;
            #pragma unroll
            for (int j = 0; j < 5; ++j)
                acc += __popc((tq[j] ^ W1Q[oc*5 + j]) & mq[j]);
            cb[oc*192 + y*16 + xx] = (s8)(nv - 2*acc);
        }
    }
    __syncthreads();
    // phase2: pool 2x2/s1 + stats, per-thread channel ownership
    {
        int c = t >> 2, q = t & 3;
        int r0 = 3*q, nr = (q < 3) ? 3 : 2;
        int rowv[4][4];
        #pragma unroll
        for (int j = 0; j < 4; ++j)
            if (j <= nr) {
                #pragma unroll
                for (int i = 0; i < 4; ++i)
                    rowv[j][i] = cmap[c*48 + (r0 + j)*4 + i];
            }
        int sum = 0, sq = 0;
        u8* gp = P1g + (size_t)b*8448 + c*176;
        #pragma unroll
        for (int pr = 0; pr < 3; ++pr) {
            if (pr < nr) {
                int o0 = 0, o1 = 0, o2 = 0, o3 = 0;
                #pragma unroll
                for (int k = 0; k < 14; ++k) {
                    int a0 = (int)(s8)(rowv[pr][k>>2] >> (8*(k&3)));
                    int a1 = (int)(s8)(rowv[pr][(k+1)>>2] >> (8*((k+1)&3)));
                    int b0 = (int)(s8)(rowv[pr+1][k>>2] >> (8*(k&3)));
                    int b1 = (int)(s8)(rowv[pr+1][(k+1)>>2] >> (8*((k+1)&3)));
                    int mx = max(max(a0, a1), max(b0, b1));
                    sum += mx; sq += mx*mx;
                    int shl = 8*(k&3);
                    if ((k>>2) == 0) o0 |= (mx & 255) << shl;
                    else if ((k>>2) == 1) o1 |= (mx & 255) << shl;
                    else if ((k>>2) == 2) o2 |= (mx & 255) << shl;
                    else o3 |= (mx & 255) << shl;
                }
                *((int4*)(gp + (r0 + pr)*16)) = make_int4(o0, o1, o2, o3);
            }
        }
        part[t] = make_int2(sum, sq);
    }
    __syncthreads();
    if (t < 48) {
        int s = 0, q = 0;
        #pragma unroll
        for (int k = 0; k < 4; ++k) { s += part[t*4+k].x; q += part[t*4+k].y; }
        int slot = b & 7;
        atomicAdd(&stats[t*8 + slot],        (u64)(long long)s);
        atomicAdd(&stats[(48 + t)*8 + slot], (u64)(long long)q);
    }
}

// ---- kA: BN1 consts, A2 masks, conv2, stats2 (no xb2 write) ----
__global__ __launch_bounds__(256)
void kA(const float* __restrict__ g1, const float* __restrict__ b1,
        const long long* __restrict__ statsIn, const u8* __restrict__ P1g,
        u64* __restrict__ A2, const u64* __restrict__ W2,
        u64* __restrict__ statsOut) {
    __shared__ float sc[48], sh[48];
    __shared__ u64 As[154];
    __shared__ short c2s[5184];    // [48][108]
    __shared__ int2 part[192];
    int t = threadIdx.x, b = blockIdx.x;
    if (t < 48) {
        long long s = 0, q = 0;
        #pragma unroll
        for (int k = 0; k < 8; ++k) { s += statsIn[t*8 + k]; q += statsIn[(48 + t)*8 + k]; }
        double N = 630784.0;   // 4096*11*14
        double mean = (double)s / N;
        double var  = (double)q / N - mean*mean;
        double scale = (double)g1[t] / sqrt(var + 1e-5);
        sc[t] = (float)scale;
        sh[t] = (float)((double)b1[t] - mean*scale);
    }
    __syncthreads();
    if (t < 154) {
        int row = t / 14, px = t - 14*row;
        const u8* pb = P1g + (size_t)b*8448 + row*16 + px;
        u64 m = 0;
        #pragma unroll
        for (int c = 0; c < 48; ++c)
            if (sc[c]*(float)(s8)pb[c*176] + sh[c] > 0.0f) m |= (1ull << c);
        As[t] = m;
        A2[(size_t)b*154 + t] = m;
    }
    __syncthreads();
    if (t < 216) {
        int pos = (t < 108) ? t : (t - 108);
        int ocb = (t < 108) ? 0 : 24;
        int oy = pos / 12, ox = pos - 12*oy;
        u64 tap[9];
        #pragma unroll
        for (int ky = 0; ky < 3; ++ky)
            #pragma unroll
            for (int kx = 0; kx < 3; ++kx)
                tap[ky*3+kx] = As[(oy+ky)*14 + ox + kx];
        #pragma unroll 4
        for (int oc = ocb; oc < ocb + 24; ++oc) {
            int acc = 0;
            #pragma unroll
            for (int k = 0; k < 9; ++k)
                acc += __popcll(tap[k] ^ W2[oc*9 + k]);
            c2s[oc*108 + pos] = (short)(432 - 2*acc);
        }
    }
    __syncthreads();
    if (t < 192) {
        int c = t >> 2, q = t & 3;
        const int* ci = (const int*)(c2s + c*108);
        int sum = 0, sq = 0;
        for (int j = q; j < 54; j += 4) {
            int v2 = ci[j];
            int lo = (int)(short)v2, hi = v2 >> 16;
            sum += lo + hi; sq += lo*lo + hi*hi;
        }
        part[t] = make_int2(sum, sq);
    }
    __syncthreads();
    if (t < 48) {
        int s = 0, q = 0;
        #pragma unroll
        for (int k = 0; k < 4; ++k) { s += part[t*4+k].x; q += part[t*4+k].y; }
        int slot = b & 7;
        atomicAdd(&statsOut[(96 + t)*8 + slot],  (u64)(long long)s);
        atomicAdd(&statsOut[(144 + t)*8 + slot], (u64)(long long)q);
    }
}

// ---- kS2: stream xb2 = sign(BN1(P1)) as float4 (grid-stride) ----
__global__ __launch_bounds__(256)
void kS2(const float* __restrict__ g1, const float* __restrict__ b1,
         const long long* __restrict__ statsIn, const u8* __restrict__ P1g,
         float* __restrict__ dout) {
    __shared__ float sc[48], sh[48];
    int t = threadIdx.x;
    if (t < 48) {
        long long s = 0, q = 0;
        #pragma unroll
        for (int k = 0; k < 8; ++k) { s += statsIn[t*8 + k]; q += statsIn[(48 + t)*8 + k]; }
        double N = 630784.0;
        double mean = (double)s / N;
        double var  = (double)q / N - mean*mean;
        double scale = (double)g1[t] / sqrt(var + 1e-5);
        sc[t] = (float)scale;
        sh[t] = (float)((double)b1[t] - mean*scale);
    }
    __syncthreads();
    float4* xo = (float4*)(dout + XB2_OFF);
    int gid = blockIdx.x*256 + t;
    for (int j = gid; j < 7569408; j += 1048576) {   // 4096*7392/4
        int base = 4*j;
        int b = base / 7392;
        int u = base - 7392*b;
        const u8* pb = P1g + (size_t)b*8448;
        float r[4];
        #pragma unroll
        for (int k = 0; k < 4; ++k) {
            int uk = u + k;
            int c = uk / 154;
            int s = uk - 154*c;
            int row = s / 14;
            int px = s - 14*row;
            int v = (int)(s8)pb[c*176 + row*16 + px];
            r[k] = fsign(sc[c]*(float)v + sh[c]);
        }
        float4 o; o.x = r[0]; o.y = r[1]; o.z = r[2]; o.w = r[3];
        xo[j] = o;
    }
}

// ---- kB: conv2 recompute + BN2 -> xb3 + A3 + conv3 + pool -> P3 + stats3 ----
__global__ __launch_bounds__(256)
void kB(const float* __restrict__ g2, const float* __restrict__ b2,
        const long long* __restrict__ statsIn, const u64* __restrict__ A2,
        const u64* __restrict__ W2, const u64* __restrict__ W3,
        float* __restrict__ dout, int* __restrict__ P3i,
        u64* __restrict__ statsOut) {
    __shared__ float sc[48], sh[48];
    __shared__ u64 As[154];
    __shared__ short c2s[5184];
    __shared__ u64 A3[108];
    __shared__ short cm[3360];
    __shared__ int2 part[192];
    int t = threadIdx.x, b = blockIdx.x;
    if (t < 154) As[t] = A2[(size_t)b*154 + t];
    if (t < 48) {
        long long s = 0, q = 0;
        #pragma unroll
        for (int k = 0; k < 8; ++k) { s += statsIn[(96 + t)*8 + k]; q += statsIn[(144 + t)*8 + k]; }
        double N = 442368.0;   // 4096*9*12
        double mean = (double)s / N;
        double var  = (double)q / N - mean*mean;
        double scale = (double)g2[t] / sqrt(var + 1e-5);
        sc[t] = (float)scale;
        sh[t] = (float)((double)b2[t] - mean*scale);
    }
    __syncthreads();
    if (t < 216) {
        int pos = (t < 108) ? t : (t - 108);
        int ocb = (t < 108) ? 0 : 24;
        int oy = pos / 12, ox = pos - 12*oy;
        u64 tap[9];
        #pragma unroll
        for (int ky = 0; ky < 3; ++ky)
            #pragma unroll
            for (int kx = 0; kx < 3; ++kx)
                tap[ky*3+kx] = As[(oy+ky)*14 + ox + kx];
        #pragma unroll 4
        for (int oc = ocb; oc < ocb + 24; ++oc) {
            int acc = 0;
            #pragma unroll
            for (int k = 0; k < 9; ++k)
                acc += __popcll(tap[k] ^ W2[oc*9 + k]);
            c2s[oc*108 + pos] = (short)(432 - 2*acc);
        }
    }
    __syncthreads();
    float4* xo = (float4*)(dout + XB3_OFF + (size_t)b*5184);
    for (int i4 = t; i4 < 1296; i4 += 256) {
        int c = i4 / 27, s4 = i4 - 27*c;
        short4 v4 = *(const short4*)&c2s[c*108 + s4*4];
        float4 o;
        o.x = fsign(sc[c]*(float)v4.x + sh[c]);
        o.y = fsign(sc[c]*(float)v4.y + sh[c]);
        o.z = fsign(sc[c]*(float)v4.z + sh[c]);
        o.w = fsign(sc[c]*(float)v4.w + sh[c]);
        xo[i4] = o;
    }
    if (t < 108) {
        u64 m = 0;
        #pragma unroll
        for (int c = 0; c < 48; ++c)
            if (sc[c]*(float)c2s[c*108 + t] + sh[c] > 0.0f) m |= (1ull << c);
        A3[t] = m;
    }
    __syncthreads();
    if (t < 210) {
        int grp = (t < 70) ? 0 : ((t < 140) ? 1 : 2);
        int pos = t - grp*70;
        int ocb = grp*16;
        int oy = pos / 10, ox = pos - 10*oy;
        u64 tap[9];
        #pragma unroll
        for (int ky = 0; ky < 3; ++ky)
            #pragma unroll
            for (int kx = 0; kx < 3; ++kx)
                tap[ky*3+kx] = A3[(oy+ky)*12 + ox + kx];
        #pragma unroll 4
        for (int oc = ocb; oc < ocb + 16; ++oc) {
            int acc = 0;
            #pragma unroll
            for (int k = 0; k < 9; ++k)
                acc += __popcll(tap[k] ^ W3[oc*9 + k]);
            cm[oc*70 + pos] = (short)(432 - 2*acc);
        }
    }
    __syncthreads();
    {
        int c = t >> 2, q = t & 3;
        if (t < 192) {
            int pr0 = (q < 2) ? 2*q : (q + 2);
            int npr = (q < 2) ? 2 : 1;
            int rowv[3][5];
            const int* cmi = (const int*)(cm + c*70);
            #pragma unroll
            for (int j = 0; j < 3; ++j)
                if (j <= npr) {
                    #pragma unroll
                    for (int i = 0; i < 5; ++i)
                        rowv[j][i] = cmi[(pr0 + j)*5 + i];
                }
            int sum = 0, sq = 0;
            int* gp = P3i + (size_t)b*1440 + c*30;
            #pragma unroll
            for (int pr = 0; pr < 2; ++pr) {
                if (pr < npr) {
                    int o[5] = {0, 0, 0, 0, 0};
                    #pragma unroll
                    for (int k = 0; k < 9; ++k) {
                        int a0 = sh16(rowv[pr][k>>1], k&1);
                        int a1 = sh16(rowv[pr][(k+1)>>1], (k+1)&1);
                        int b0 = sh16(rowv[pr+1][k>>1], k&1);
                        int b1 = sh16(rowv[pr+1][(k+1)>>1], (k+1)&1);
                        int mx = max(max(a0, a1), max(b0, b1));
                        sum += mx; sq += mx*mx;
                        o[k>>1] |= (mx & 0xffff) << (16*(k&1));
                    }
                    #pragma unroll
                    for (int j = 0; j < 5; ++j) gp[(pr0 + pr)*5 + j] = o[j];
                }
            }
            part[t] = make_int2(sum, sq);
        }
    }
    __syncthreads();
    if (t < 48) {
        int s = 0, q = 0;
        #pragma unroll
        for (int k = 0; k < 4; ++k) { s += part[t*4+k].x; q += part[t*4+k].y; }
        int slot = b & 7;
        atomicAdd(&statsOut[(192 + t)*8 + slot], (u64)(long long)s);
        atomicAdd(&statsOut[(240 + t)*8 + slot], (u64)(long long)q);
    }
}

// ---- kC: BN3 apply -> fb + FC ----
__global__ __launch_bounds__(256)
void kC(const float* __restrict__ g3, const float* __restrict__ b3,
        const long long* __restrict__ statsIn, const int4* __restrict__ P3g4,
        const u64* __restrict__ WFC, float* __restrict__ dout) {
    __shared__ float sc[48], sh[48];
    __shared__ int smP[1440];      // padded pooled3 shorts [48][60]
    __shared__ u8 nib[648];
    __shared__ u64 fbb[41];
    int t = threadIdx.x, b = blockIdx.x;
    for (int i = t; i < 360; i += 256) ((int4*)smP)[i] = P3g4[(size_t)b*360 + i];
    if (t < 48) {
        long long s = 0, q = 0;
        #pragma unroll
        for (int k = 0; k < 8; ++k) { s += statsIn[(192 + t)*8 + k]; q += statsIn[(240 + t)*8 + k]; }
        double N = 221184.0;   // 4096*6*9
        double mean = (double)s / N;
        double var  = (double)q / N - mean*mean;
        double scale = (double)g3[t] / sqrt(var + 1e-5);
        sc[t] = (float)scale;
        sh[t] = (float)((double)b3[t] - mean*scale);
    }
    __syncthreads();
    const short* smS = (const short*)smP;
    float4* fo = (float4*)(dout + FB_OFF + (size_t)b*2592);
    for (int i4 = t; i4 < 648; i4 += 256) {
        int i = 4*i4;
        float r[4];
        unsigned n = 0;
        #pragma unroll
        for (int k = 0; k < 4; ++k) {
            int idx = i + k;
            int c = idx / 54, s = idx - 54*c;
            int row = s / 9, px = s - 9*row;
            float bn = sc[c]*(float)smS[c*60 + row*10 + px] + sh[c];
            r[k] = fsign(bn);
            if (bn > 0.0f) n |= (1u << k);
        }
        float4 o; o.x = r[0]; o.y = r[1]; o.z = r[2]; o.w = r[3];
        fo[i4] = o;
        nib[i4] = (u8)n;
    }
    __syncthreads();
    if (t < 41) {
        u64 m = 0;
        #pragma unroll
        for (int k = 0; k < 16; ++k) {
            int j = t*16 + k;
            if (j < 648) m |= ((u64)nib[j]) << (4*k);
        }
        fbb[t] = m;
    }
    __syncthreads();
    if (t < 5) {
        const u64* Wf = WFC + t*41;
        int acc = 0;
        #pragma unroll
        for (int j = 0; j < 41; ++j) acc += __popcll(fbb[j] ^ Wf[j]);
        dout[OUT_OFF + b*5 + t] = (float)(2592 - 2*acc);
    }
}

extern "C" void kernel_launch(void* const* d_in, const int* in_sizes, int n_in,
                              void* d_out, int out_size, void* d_ws, size_t ws_size,
                              hipStream_t stream) {
    const float* x   = (const float*)d_in[0];
    const float* w1  = (const float*)d_in[1];
    const float* g1  = (const float*)d_in[2];
    const float* b1  = (const float*)d_in[3];
    const float* w2  = (const float*)d_in[4];
    const float* g2  = (const float*)d_in[5];
    const float* b2  = (const float*)d_in[6];
    const float* w3  = (const float*)d_in[7];
    const float* g3  = (const float*)d_in[8];
    const float* b3  = (const float*)d_in[9];
    const float* wfc = (const float*)d_in[10];
    float* out = (float*)d_out;
    char* ws = (char*)d_ws;

    long long* stats = (long long*)(ws + WS_STATS);
    u32*       W1Q   = (u32*)(ws + WS_W1Q);
    u64*       W2P   = (u64*)(ws + WS_W2P);
    u64*       W3P   = (u64*)(ws + WS_W3P);
    u64*       WFCP  = (u64*)(ws + WS_WFCP);
    u64*       A2    = (u64*)(ws + WS_A2);
    u8*        P1g   = (u8*)(ws + WS_P1);
    int*       P3i   = (int*)(ws + WS_P3);

    hipLaunchKernelGGL(kw_pack, dim3(1),    dim3(512), 0, stream,
                       w1, w2, w3, wfc, W1Q, W2P, W3P, WFCP, stats);
    hipLaunchKernelGGL(k1,      dim3(NB),   dim3(192), 0, stream,
                       x, W1Q, out, P1g, (u64*)stats);
    hipLaunchKernelGGL(kA,      dim3(NB),   dim3(256), 0, stream,
                       g1, b1, stats, P1g, A2, W2P, (u64*)stats);
    hipLaunchKernelGGL(kS2,     dim3(NB),   dim3(256), 0, stream,
                       g1, b1, stats, P1g, out);
    hipLaunchKernelGGL(kB,      dim3(NB),   dim3(256), 0, stream,
                       g2, b2, stats, A2, W2P, W3P, out, P3i, (u64*)stats);
    hipLaunchKernelGGL(kC,      dim3(NB),   dim3(256), 0, stream,
                       g3, b3, stats, (const int4*)P3i, WFCP, out);
}